// Round 8
// baseline (634.092 us; speedup 1.0000x reference)
//
#include <hip/hip_runtime.h>
#include <cstdint>
#include <cstddef>

// ---- problem constants ----
static constexpr int S_LEN = 2048;
static constexpr int HID   = 2048;
static constexpr int NH    = 32;
static constexpr int HD    = 128;
static constexpr int OD    = 4096;    // NH*HD
static constexpr int QKV_O = 12288;   // 3*OD

#define AS1 __attribute__((address_space(1)))
#define AS3 __attribute__((address_space(3)))

typedef __attribute__((ext_vector_type(8))) short bf16x8;
typedef __attribute__((ext_vector_type(4))) float f32x4;
typedef __attribute__((ext_vector_type(4))) short s16x4;

__device__ __forceinline__ short f2bf(float f) {
  unsigned u = __float_as_uint(f);
  unsigned r = (u + 0x7fffu + ((u >> 16) & 1u)) >> 16;   // RNE
  return (short)r;
}
__device__ __forceinline__ float bf2f(short s) {
  return __uint_as_float(((unsigned)(unsigned short)s) << 16);
}

// ---------------- fp32 -> bf16 convert (bandwidth-bound) ----------------
__global__ void convert_kernel(const float* __restrict__ in, short* __restrict__ out, int n4) {
  int i = blockIdx.x * blockDim.x + threadIdx.x;
  if (i >= n4) return;
  float4 f = ((const float4*)in)[i];
  s16x4 s;
  s.x = f2bf(f.x); s.y = f2bf(f.y); s.z = f2bf(f.z); s.w = f2bf(f.w);
  ((s16x4*)out)[i] = s;
}

// ---------------- NT GEMM: C[M,N] = A[M,K](bf16) * B[N,K]^T ----------------
// BF32: 1 = B is fp32 read directly (staged f32 via global_load_lds, cvt at frag load).
// CMODE: 0 = bf16 C, 1 = fp32 C.  ldc = C row stride (elements).
#define BM 128
#define BN 128
#define BK 32

template <int BF32, int CMODE>
__global__ __launch_bounds__(256, 2) void gemm_nt(
    const short* __restrict__ A, const void* __restrict__ Bp, void* __restrict__ Cp,
    int K, int ldc) {
  __shared__ short Alds[BM * BK];                    // 8 KB
  __shared__ short Blds[BN * BK * (BF32 ? 2 : 1)];   // 8/16 KB (f32 tile when BF32)
  const int tid  = threadIdx.x;
  const int lane = tid & 63;
  const int quad = lane >> 4;
  const int col  = lane & 15;
  const int wave = tid >> 6;
  const int m0 = blockIdx.y * BM;
  const int n0 = blockIdx.x * BN;
  const int wm = (wave & 1) * 64;
  const int wn = (wave >> 1) * 64;

  f32x4 acc[4][4] = {};

  for (int k0 = 0; k0 < K; k0 += BK) {
    __syncthreads();
    // --- stage A (bf16, 8KB = 512 x 16B chunks) ---
#pragma unroll
    for (int it = 0; it < 2; ++it) {
      int idx = it * 256 + tid;
      int row = idx >> 2;
      int ce  = (idx & 3) * 8;
      const short* ga = A + (size_t)(m0 + row) * K + k0 + ce;
      __builtin_amdgcn_global_load_lds((const AS1 unsigned*)ga, (AS3 unsigned*)&Alds[idx * 8], 16, 0, 0);
    }
    // --- stage B ---
    if (BF32) {
      float* B32 = (float*)Blds;                      // 16KB = 1024 x 16B chunks
#pragma unroll
      for (int it = 0; it < 4; ++it) {
        int idx = it * 256 + tid;
        int row = idx >> 3;
        int ce  = (idx & 7) * 4;                      // f32 elements
        const float* gb = (const float*)Bp + (size_t)(n0 + row) * K + k0 + ce;
        __builtin_amdgcn_global_load_lds((const AS1 unsigned*)gb, (AS3 unsigned*)&B32[idx * 4], 16, 0, 0);
      }
    } else {
#pragma unroll
      for (int it = 0; it < 2; ++it) {
        int idx = it * 256 + tid;
        int row = idx >> 2;
        int ce  = (idx & 3) * 8;
        const short* gb = (const short*)Bp + (size_t)(n0 + row) * K + k0 + ce;
        __builtin_amdgcn_global_load_lds((const AS1 unsigned*)gb, (AS3 unsigned*)&Blds[idx * 8], 16, 0, 0);
      }
    }
    __syncthreads();

    bf16x8 a[4], b[4];
#pragma unroll
    for (int i = 0; i < 4; ++i) {
      a[i] = *(const bf16x8*)&Alds[(wm + i * 16 + col) * BK + quad * 8];
      if (BF32) {
        const float* src = (const float*)Blds + (size_t)(wn + i * 16 + col) * BK + quad * 8;
        bf16x8 v;
#pragma unroll
        for (int j = 0; j < 8; ++j) v[j] = f2bf(src[j]);
        b[i] = v;
      } else {
        b[i] = *(const bf16x8*)&Blds[(wn + i * 16 + col) * BK + quad * 8];
      }
    }
#pragma unroll
    for (int i = 0; i < 4; ++i)
#pragma unroll
      for (int j = 0; j < 4; ++j)
        acc[i][j] = __builtin_amdgcn_mfma_f32_16x16x32_bf16(a[i], b[j], acc[i][j], 0, 0, 0);
  }

  // epilogue: C/D layout col=lane&15, row=quad*4+reg (verified m89/m91)
#pragma unroll
  for (int i = 0; i < 4; ++i)
#pragma unroll
    for (int j = 0; j < 4; ++j)
#pragma unroll
      for (int r = 0; r < 4; ++r) {
        int rr = m0 + wm + i * 16 + quad * 4 + r;
        int cc = n0 + wn + j * 16 + col;
        if (CMODE == 1)
          ((float*)Cp)[(size_t)rr * ldc + cc] = acc[i][j][r];
        else
          ((short*)Cp)[(size_t)rr * ldc + cc] = f2bf(acc[i][j][r]);
      }
}

// ---------------- per-(s, q/k, head) RMSNorm + RoPE, in place on bf16 qkv ----------------
// Q rows are additionally pre-scaled by scale*log2(e) = 128^-0.5 * 1.4427 (softmax folding).
__global__ void norm_rope_kernel(short* __restrict__ qkv,
                                 const int* __restrict__ positions,
                                 const float* __restrict__ qw,
                                 const float* __restrict__ kw) {
  int item = blockIdx.x * 4 + (threadIdx.x >> 6);  // (s, which, head)
  int lane = threadIdx.x & 63;
  int head  = item & 31;
  int which = (item >> 5) & 1;
  int s     = item >> 6;
  const float* w = which ? kw : qw;
  short* base = qkv + (size_t)s * QKV_O + which * OD + head * HD;

  float x1 = bf2f(base[lane]);
  float x2 = bf2f(base[lane + 64]);
  float ss = x1 * x1 + x2 * x2;
#pragma unroll
  for (int d = 32; d; d >>= 1) ss += __shfl_xor(ss, d);
  float r = rsqrtf(ss * (1.0f / 128.0f) + 1e-5f);
  float xn1 = x1 * r * w[lane];
  float xn2 = x2 * r * w[lane + 64];

  float pos = (float)positions[s];
  float inv_freq = exp2f((float)lane * (-13.287712379549449f / 64.0f));
  float f = pos * inv_freq;
  float c = cosf(f), sn = sinf(f);
  float sc = which ? 1.0f : 0.12751863738f;   // q: fold scale*log2(e)
  base[lane]      = f2bf((xn1 * c - xn2 * sn) * sc);
  base[lane + 64] = f2bf((xn2 * c + xn1 * sn) * sc);
}

// ---------------- V pre-transpose: qkv V region -> vtp[h][kt][d][64] tiles ----------------
__global__ void packv_kernel(const short* __restrict__ qkv, short* __restrict__ vtp) {
  __shared__ short T[64][136];   // +8 pad
  const int h  = blockIdx.x;
  const int kt = blockIdx.y;
  const int tid = threadIdx.x;
  {
    int rr = tid >> 2;
    int db = (tid & 3) * 32;
    const short* src = qkv + (size_t)(kt * 64 + rr) * QKV_O + 2 * OD + h * HD + db;
#pragma unroll
    for (int i = 0; i < 4; ++i)
      *(bf16x8*)&T[rr][db + i * 8] = *(const bf16x8*)(src + i * 8);
  }
  __syncthreads();
  {
    int d  = tid >> 1;
    int k0 = (tid & 1) * 32;
    short* dst = vtp + (((size_t)h * 32 + kt) * 128 + d) * 64 + k0;
#pragma unroll
    for (int c = 0; c < 4; ++c) {
      bf16x8 v;
#pragma unroll
      for (int j = 0; j < 8; ++j) v[j] = T[k0 + c * 8 + j][d];
      *(bf16x8*)&dst[c * 8] = v;
    }
  }
}

// ---------------- flash attention (causal), Bq=64/Bk=64 paired, swizzled LDS ----------------
// Q is pre-scaled (norm_rope) so scores are already log2-domain: softmax uses exp2 directly.
// Swizzles (8-elem chunk granularity):
//   K  (key,d): key*128 + ((d>>3) ^ (key&15))*8 + (d&7)
//   Vt (d,key): d*64  + ((key>>3) ^ (d&7))*8 + (key&7)
//   P  (row,key) per wave: row*64 + ((key>>3) ^ (row&7))*8 + (key&7)
__global__ __launch_bounds__(256, 2) void attn_kernel(
    const short* __restrict__ qkv, const short* __restrict__ vtp, short* __restrict__ obuf) {
  __shared__ short Klds[64 * 128];     // 16 KB
  __shared__ short Vt[128 * 64];       // 16 KB
  __shared__ short Plds[4][16 * 64];   //  8 KB

  const int tid  = threadIdx.x;
  const int lane = tid & 63;
  const int wave = tid >> 6;
  const int quad = lane >> 4;
  const int col  = lane & 15;
  const int h    = blockIdx.y;

#pragma unroll 1
  for (int half = 0; half < 2; ++half) {
    const int qt = half == 0 ? blockIdx.x : 31 - blockIdx.x;   // paired: 33 k-iters/block
    const int qbase = qt * 64 + wave * 16;

    bf16x8 qf[4];
#pragma unroll
    for (int kf = 0; kf < 4; ++kf)
      qf[kf] = *(const bf16x8*)(qkv + (size_t)(qbase + col) * QKV_O + h * HD + kf * 32 + quad * 8);

    f32x4 o[8] = {};
    float m_r[4], l_i[4];
#pragma unroll
    for (int r = 0; r < 4; ++r) { m_r[r] = -1e30f; l_i[r] = 0.f; }

    for (int kt = 0; kt <= qt; ++kt) {
      __syncthreads();
      {
        int r  = tid >> 2;            // key 0..63
        int cb = (tid & 3) * 32;
        const short* kp = qkv + (size_t)(kt * 64 + r) * QKV_O + OD + h * HD + cb;
#pragma unroll
        for (int i = 0; i < 4; ++i) {
          int swz = ((tid & 3) * 4 + i) ^ (r & 15);
          *(bf16x8*)&Klds[r * 128 + swz * 8] = *(const bf16x8*)(kp + i * 8);
        }
        int vd = tid >> 1;            // d 0..127
        const short* vp = vtp + (((size_t)h * 32 + kt) * 128 + vd) * 64 + (tid & 1) * 32;
#pragma unroll
        for (int i = 0; i < 4; ++i) {
          int swz = ((tid & 1) * 4 + i) ^ (vd & 7);
          *(bf16x8*)&Vt[vd * 64 + swz * 8] = *(const bf16x8*)(vp + i * 8);
        }
      }
      __syncthreads();

      // S = Q K^T : 4 nf (keys) x 4 kf (d-steps)
      f32x4 sfr[4];
#pragma unroll
      for (int nf = 0; nf < 4; ++nf) {
        f32x4 acc = {};
#pragma unroll
        for (int kf = 0; kf < 4; ++kf) {
          bf16x8 b = *(const bf16x8*)&Klds[(nf * 16 + col) * 128 + ((kf * 4 + quad) ^ col) * 8];
          acc = __builtin_amdgcn_mfma_f32_16x16x32_bf16(qf[kf], b, acc, 0, 0, 0);
        }
        sfr[nf] = acc;
      }

      if (kt == qt) {   // diagonal tile: causal mask
#pragma unroll
        for (int nf = 0; nf < 4; ++nf)
#pragma unroll
          for (int r = 0; r < 4; ++r) {
            int key = kt * 64 + nf * 16 + col;
            int qg  = qbase + quad * 4 + r;
            if (key > qg) sfr[nf][r] = -1e30f;
          }
      }

      // online softmax (log2 domain, per-lane partial l)
#pragma unroll
      for (int r = 0; r < 4; ++r) {
        float mt = fmaxf(fmaxf(sfr[0][r], sfr[1][r]), fmaxf(sfr[2][r], sfr[3][r]));
#pragma unroll
        for (int d = 8; d; d >>= 1) mt = fmaxf(mt, __shfl_xor(mt, d));
        float mnew  = fmaxf(m_r[r], mt);
        float alpha = exp2f(m_r[r] - mnew);
        float ps = 0.f;
#pragma unroll
        for (int nf = 0; nf < 4; ++nf) {
          float p = exp2f(sfr[nf][r] - mnew);
          sfr[nf][r] = p;
          ps += p;
        }
        l_i[r] = l_i[r] * alpha + ps;
        m_r[r] = mnew;
#pragma unroll
        for (int nf = 0; nf < 8; ++nf) o[nf][r] *= alpha;
      }

      // P -> per-wave LDS (C-layout scatter -> A-layout rows), swizzled; no barrier needed
#pragma unroll
      for (int nf = 0; nf < 4; ++nf)
#pragma unroll
        for (int r = 0; r < 4; ++r) {
          int row = quad * 4 + r;
          int key = nf * 16 + col;
          Plds[wave][row * 64 + ((key >> 3) ^ (row & 7)) * 8 + (key & 7)] = f2bf(sfr[nf][r]);
        }

      // O += P V
      bf16x8 pa[2];
#pragma unroll
      for (int kf = 0; kf < 2; ++kf)
        pa[kf] = *(const bf16x8*)&Plds[wave][col * 64 + ((kf * 4 + quad) ^ (col & 7)) * 8];
#pragma unroll
      for (int nf = 0; nf < 8; ++nf)
#pragma unroll
        for (int kf = 0; kf < 2; ++kf) {
          bf16x8 vb = *(const bf16x8*)&Vt[(nf * 16 + col) * 64 + ((kf * 4 + quad) ^ (col & 7)) * 8];
          o[nf] = __builtin_amdgcn_mfma_f32_16x16x32_bf16(pa[kf], vb, o[nf], 0, 0, 0);
        }
    }

    // epilogue: reduce per-lane l across the 16-lane row group, O /= l, write bf16
#pragma unroll
    for (int r = 0; r < 4; ++r) {
      float lt = l_i[r];
#pragma unroll
      for (int d = 8; d; d >>= 1) lt += __shfl_xor(lt, d);
      float inv = 1.0f / lt;
      int sg = qbase + quad * 4 + r;
#pragma unroll
      for (int nf = 0; nf < 8; ++nf)
        obuf[(size_t)sg * OD + h * HD + nf * 16 + col] = f2bf(o[nf][r] * inv);
    }
  }
}

// ---------------- launcher ----------------
extern "C" void kernel_launch(void* const* d_in, const int* in_sizes, int n_in,
                              void* d_out, int out_size, void* d_ws, size_t ws_size,
                              hipStream_t stream) {
  (void)in_sizes; (void)n_in; (void)out_size; (void)ws_size;
  const float* hs   = (const float*)d_in[0];   // [2048][2048] f32
  const int*   pos  = (const int*)d_in[1];     // [2048] int32
  const float* qkvw = (const float*)d_in[2];   // [12288][2048] f32
  const float* qw   = (const float*)d_in[3];   // [128] f32
  const float* kw   = (const float*)d_in[4];   // [128] f32
  const float* ow   = (const float*)d_in[5];   // [2048][4096] f32
  float* out = (float*)d_out;                  // [2048][2048] f32

  // Memory plan: ws[0..48M) qkvb, ws[48..64M) obuf.
  // d_out: hsb (bf16 hidden) during GEMM1 -> vtp (packed V^T) -> final out (GEMM2).
  char* ws = (char*)d_ws;
  short* qkvb = (short*)(ws);
  short* obuf = (short*)(ws + 50331648);
  short* hsb  = (short*)d_out;
  short* vtp  = (short*)d_out;

  // 1) convert hidden_states -> bf16 (in d_out scratch)
  {
    int n4 = (S_LEN * HID) / 4;
    convert_kernel<<<(n4 + 255) / 256, 256, 0, stream>>>(hs, hsb, n4);
  }

  // 2) qkv = hs @ qkv_w^T, single launch, B read as f32 (M=2048, N=12288, K=2048)
  gemm_nt<1, 0><<<dim3(QKV_O / BN, S_LEN / BM), 256, 0, stream>>>(
      hsb, qkvw, qkvb, HID, QKV_O);

  // 3) RMSNorm + RoPE in place on q,k (q pre-scaled by scale*log2e)
  norm_rope_kernel<<<(S_LEN * 2 * NH) / 4, 256, 0, stream>>>(qkvb, pos, qw, kw);

  // 4) pack V^T tiles into d_out (hsb dead after GEMM1)
  packv_kernel<<<dim3(NH, S_LEN / 64), 256, 0, stream>>>(qkvb, vtp);

  // 5) causal flash attention -> obuf [s][h*128+d] (bf16)
  attn_kernel<<<dim3(16, NH), 256, 0, stream>>>(qkvb, vtp, obuf);

  // 6) out = obuf @ o_proj_w^T, B read as f32 (M=2048, N=2048, K=4096), fp32 C
  gemm_nt<1, 1><<<dim3(HID / BN, S_LEN / BM), 256, 0, stream>>>(
      obuf, ow, out, OD, HID);
}

// Round 9
// 583.721 us; speedup vs baseline: 1.0863x; 1.0863x over previous
//
#include <hip/hip_runtime.h>
#include <cstdint>
#include <cstddef>

// ---- problem constants ----
static constexpr int S_LEN = 2048;
static constexpr int HID   = 2048;
static constexpr int NH    = 32;
static constexpr int HD    = 128;
static constexpr int OD    = 4096;    // NH*HD
static constexpr int QKV_O = 12288;   // 3*OD

#define AS1 __attribute__((address_space(1)))
#define AS3 __attribute__((address_space(3)))

typedef __attribute__((ext_vector_type(8))) short bf16x8;
typedef __attribute__((ext_vector_type(4))) float f32x4;
typedef __attribute__((ext_vector_type(4))) short s16x4;

__device__ __forceinline__ short f2bf(float f) {
  unsigned u = __float_as_uint(f);
  unsigned r = (u + 0x7fffu + ((u >> 16) & 1u)) >> 16;   // RNE
  return (short)r;
}
__device__ __forceinline__ float bf2f(short s) {
  return __uint_as_float(((unsigned)(unsigned short)s) << 16);
}

// ---------------- fp32 -> bf16 convert (bandwidth-bound) ----------------
__global__ void convert_kernel(const float* __restrict__ in, short* __restrict__ out, int n4) {
  int i = blockIdx.x * blockDim.x + threadIdx.x;
  if (i >= n4) return;
  float4 f = ((const float4*)in)[i];
  s16x4 s;
  s.x = f2bf(f.x); s.y = f2bf(f.y); s.z = f2bf(f.z); s.w = f2bf(f.w);
  ((s16x4*)out)[i] = s;
}

// ---------------- NT GEMM: C[M,N] = A[M,K](bf16) * B[N,K]^T(f32, direct) ----------------
// B f32 tile is stored XOR-swizzled in LDS: dword-group g of row r lives at chunk r*8+(g^(r&7)).
// global_load_lds can realize this because we permute the SOURCE address per lane (LDS dest
// layout is fixed wave-linear).  Fragment reads then hit the b128 bank floor (8-way).
// BNT: tile N (128 or 64).  CMODE: 0 = bf16 C, 1 = fp32 C.  ldc = C row stride.
#define BM 128
#define BK 32

template <int BNT, int CMODE>
__global__ __launch_bounds__(256, 2) void gemm_nt_f32w(
    const short* __restrict__ A, const float* __restrict__ B, void* __restrict__ Cp,
    int K, int ldc) {
  __shared__ short Alds[BM * BK];      // 8 KB bf16
  __shared__ float B32[BNT * BK];      // 16/8 KB f32, swizzled
  constexpr int WN = BNT / 2;          // per-wave cols
  constexpr int NJ = WN / 16;          // B frags per wave
  constexpr int BIT = BNT * 8 / 256;   // B staging iterations (16B chunks)
  const int tid  = threadIdx.x;
  const int lane = tid & 63;
  const int quad = lane >> 4;
  const int col  = lane & 15;
  const int wave = tid >> 6;
  const int m0 = blockIdx.y * BM;
  const int n0 = blockIdx.x * BNT;
  const int wm = (wave & 1) * 64;
  const int wn = (wave >> 1) * WN;

  f32x4 acc[4][NJ] = {};

  for (int k0 = 0; k0 < K; k0 += BK) {
    __syncthreads();
    // --- stage A (bf16, 512 x 16B chunks, linear) ---
#pragma unroll
    for (int it = 0; it < 2; ++it) {
      int idx = it * 256 + tid;
      int row = idx >> 2;
      int ce  = (idx & 3) * 8;
      const short* ga = A + (size_t)(m0 + row) * K + k0 + ce;
      __builtin_amdgcn_global_load_lds((const AS1 unsigned*)ga, (AS3 unsigned*)&Alds[idx * 8], 16, 0, 0);
    }
    // --- stage B (f32, source-permuted so LDS is chunk-swizzled) ---
#pragma unroll
    for (int it = 0; it < BIT; ++it) {
      int idx  = it * 256 + tid;        // LDS 16B-chunk index
      int row  = idx >> 3;
      int gsrc = (idx & 7) ^ (row & 7); // inverse swizzle on the source
      const float* gb = B + (size_t)(n0 + row) * K + k0 + gsrc * 4;
      __builtin_amdgcn_global_load_lds((const AS1 unsigned*)gb, (AS3 unsigned*)&B32[idx * 4], 16, 0, 0);
    }
    __syncthreads();

    bf16x8 a[4], b[NJ];
#pragma unroll
    for (int i = 0; i < 4; ++i)
      a[i] = *(const bf16x8*)&Alds[(wm + i * 16 + col) * BK + quad * 8];
#pragma unroll
    for (int j = 0; j < NJ; ++j) {
      int row = wn + j * 16 + col;
      int r7  = row & 7;
      bf16x8 v;
#pragma unroll
      for (int j4 = 0; j4 < 2; ++j4) {
        int g = quad * 2 + j4;
        const float4 f = *(const float4*)&B32[(row * 8 + (g ^ r7)) * 4];
        v[j4 * 4 + 0] = f2bf(f.x); v[j4 * 4 + 1] = f2bf(f.y);
        v[j4 * 4 + 2] = f2bf(f.z); v[j4 * 4 + 3] = f2bf(f.w);
      }
      b[j] = v;
    }
#pragma unroll
    for (int i = 0; i < 4; ++i)
#pragma unroll
      for (int j = 0; j < NJ; ++j)
        acc[i][j] = __builtin_amdgcn_mfma_f32_16x16x32_bf16(a[i], b[j], acc[i][j], 0, 0, 0);
  }

  // epilogue: C/D layout col=lane&15, row=quad*4+reg (verified m89/m91)
#pragma unroll
  for (int i = 0; i < 4; ++i)
#pragma unroll
    for (int j = 0; j < NJ; ++j)
#pragma unroll
      for (int r = 0; r < 4; ++r) {
        int rr = m0 + wm + i * 16 + quad * 4 + r;
        int cc = n0 + wn + j * 16 + col;
        if (CMODE == 1)
          ((float*)Cp)[(size_t)rr * ldc + cc] = acc[i][j][r];
        else
          ((short*)Cp)[(size_t)rr * ldc + cc] = f2bf(acc[i][j][r]);
      }
}

// ---------------- per-(s, q/k, head) RMSNorm + RoPE, in place on bf16 qkv ----------------
// Q rows are additionally pre-scaled by scale*log2(e) (softmax folding).
__global__ void norm_rope_kernel(short* __restrict__ qkv,
                                 const int* __restrict__ positions,
                                 const float* __restrict__ qw,
                                 const float* __restrict__ kw) {
  int item = blockIdx.x * 4 + (threadIdx.x >> 6);  // (s, which, head)
  int lane = threadIdx.x & 63;
  int head  = item & 31;
  int which = (item >> 5) & 1;
  int s     = item >> 6;
  const float* w = which ? kw : qw;
  short* base = qkv + (size_t)s * QKV_O + which * OD + head * HD;

  float x1 = bf2f(base[lane]);
  float x2 = bf2f(base[lane + 64]);
  float ss = x1 * x1 + x2 * x2;
#pragma unroll
  for (int d = 32; d; d >>= 1) ss += __shfl_xor(ss, d);
  float r = rsqrtf(ss * (1.0f / 128.0f) + 1e-5f);
  float xn1 = x1 * r * w[lane];
  float xn2 = x2 * r * w[lane + 64];

  float pos = (float)positions[s];
  float inv_freq = exp2f((float)lane * (-13.287712379549449f / 64.0f));
  float f = pos * inv_freq;
  float c = cosf(f), sn = sinf(f);
  float sc = which ? 1.0f : 0.12751863738f;   // q: fold scale*log2(e)
  base[lane]      = f2bf((xn1 * c - xn2 * sn) * sc);
  base[lane + 64] = f2bf((xn2 * c + xn1 * sn) * sc);
}

// ---------------- V pre-transpose: qkv V region -> vtp[h][kt][d][64] tiles ----------------
__global__ void packv_kernel(const short* __restrict__ qkv, short* __restrict__ vtp) {
  __shared__ short T[64][136];   // +8 pad
  const int h  = blockIdx.x;
  const int kt = blockIdx.y;
  const int tid = threadIdx.x;
  {
    int rr = tid >> 2;
    int db = (tid & 3) * 32;
    const short* src = qkv + (size_t)(kt * 64 + rr) * QKV_O + 2 * OD + h * HD + db;
#pragma unroll
    for (int i = 0; i < 4; ++i)
      *(bf16x8*)&T[rr][db + i * 8] = *(const bf16x8*)(src + i * 8);
  }
  __syncthreads();
  {
    int d  = tid >> 1;
    int k0 = (tid & 1) * 32;
    short* dst = vtp + (((size_t)h * 32 + kt) * 128 + d) * 64 + k0;
#pragma unroll
    for (int c = 0; c < 4; ++c) {
      bf16x8 v;
#pragma unroll
      for (int j = 0; j < 8; ++j) v[j] = T[k0 + c * 8 + j][d];
      *(bf16x8*)&dst[c * 8] = v;
    }
  }
}

// ---------------- flash attention (causal), Bq=64/Bk=64 paired, swizzled LDS ----------------
__global__ __launch_bounds__(256, 2) void attn_kernel(
    const short* __restrict__ qkv, const short* __restrict__ vtp, short* __restrict__ obuf) {
  __shared__ short Klds[64 * 128];     // 16 KB
  __shared__ short Vt[128 * 64];       // 16 KB
  __shared__ short Plds[4][16 * 64];   //  8 KB

  const int tid  = threadIdx.x;
  const int lane = tid & 63;
  const int wave = tid >> 6;
  const int quad = lane >> 4;
  const int col  = lane & 15;
  const int h    = blockIdx.y;

#pragma unroll 1
  for (int half = 0; half < 2; ++half) {
    const int qt = half == 0 ? blockIdx.x : 31 - blockIdx.x;   // paired: 33 k-iters/block
    const int qbase = qt * 64 + wave * 16;

    bf16x8 qf[4];
#pragma unroll
    for (int kf = 0; kf < 4; ++kf)
      qf[kf] = *(const bf16x8*)(qkv + (size_t)(qbase + col) * QKV_O + h * HD + kf * 32 + quad * 8);

    f32x4 o[8] = {};
    float m_r[4], l_i[4];
#pragma unroll
    for (int r = 0; r < 4; ++r) { m_r[r] = -1e30f; l_i[r] = 0.f; }

    for (int kt = 0; kt <= qt; ++kt) {
      __syncthreads();
      {
        int r  = tid >> 2;            // key 0..63
        int cb = (tid & 3) * 32;
        const short* kp = qkv + (size_t)(kt * 64 + r) * QKV_O + OD + h * HD + cb;
#pragma unroll
        for (int i = 0; i < 4; ++i) {
          int swz = ((tid & 3) * 4 + i) ^ (r & 15);
          *(bf16x8*)&Klds[r * 128 + swz * 8] = *(const bf16x8*)(kp + i * 8);
        }
        int vd = tid >> 1;            // d 0..127
        const short* vp = vtp + (((size_t)h * 32 + kt) * 128 + vd) * 64 + (tid & 1) * 32;
#pragma unroll
        for (int i = 0; i < 4; ++i) {
          int swz = ((tid & 1) * 4 + i) ^ (vd & 7);
          *(bf16x8*)&Vt[vd * 64 + swz * 8] = *(const bf16x8*)(vp + i * 8);
        }
      }
      __syncthreads();

      // S = Q K^T
      f32x4 sfr[4];
#pragma unroll
      for (int nf = 0; nf < 4; ++nf) {
        f32x4 acc = {};
#pragma unroll
        for (int kf = 0; kf < 4; ++kf) {
          bf16x8 b = *(const bf16x8*)&Klds[(nf * 16 + col) * 128 + ((kf * 4 + quad) ^ col) * 8];
          acc = __builtin_amdgcn_mfma_f32_16x16x32_bf16(qf[kf], b, acc, 0, 0, 0);
        }
        sfr[nf] = acc;
      }

      if (kt == qt) {   // diagonal tile: causal mask
#pragma unroll
        for (int nf = 0; nf < 4; ++nf)
#pragma unroll
          for (int r = 0; r < 4; ++r) {
            int key = kt * 64 + nf * 16 + col;
            int qg  = qbase + quad * 4 + r;
            if (key > qg) sfr[nf][r] = -1e30f;
          }
      }

      // online softmax (log2 domain, per-lane partial l)
#pragma unroll
      for (int r = 0; r < 4; ++r) {
        float mt = fmaxf(fmaxf(sfr[0][r], sfr[1][r]), fmaxf(sfr[2][r], sfr[3][r]));
#pragma unroll
        for (int d = 8; d; d >>= 1) mt = fmaxf(mt, __shfl_xor(mt, d));
        float mnew  = fmaxf(m_r[r], mt);
        float alpha = exp2f(m_r[r] - mnew);
        float ps = 0.f;
#pragma unroll
        for (int nf = 0; nf < 4; ++nf) {
          float p = exp2f(sfr[nf][r] - mnew);
          sfr[nf][r] = p;
          ps += p;
        }
        l_i[r] = l_i[r] * alpha + ps;
        m_r[r] = mnew;
#pragma unroll
        for (int nf = 0; nf < 8; ++nf) o[nf][r] *= alpha;
      }

      // P -> per-wave LDS (C-layout scatter -> A-layout rows), swizzled
#pragma unroll
      for (int nf = 0; nf < 4; ++nf)
#pragma unroll
        for (int r = 0; r < 4; ++r) {
          int row = quad * 4 + r;
          int key = nf * 16 + col;
          Plds[wave][row * 64 + ((key >> 3) ^ (row & 7)) * 8 + (key & 7)] = f2bf(sfr[nf][r]);
        }

      // O += P V
      bf16x8 pa[2];
#pragma unroll
      for (int kf = 0; kf < 2; ++kf)
        pa[kf] = *(const bf16x8*)&Plds[wave][col * 64 + ((kf * 4 + quad) ^ (col & 7)) * 8];
#pragma unroll
      for (int nf = 0; nf < 8; ++nf)
#pragma unroll
        for (int kf = 0; kf < 2; ++kf) {
          bf16x8 vb = *(const bf16x8*)&Vt[(nf * 16 + col) * 64 + ((kf * 4 + quad) ^ (col & 7)) * 8];
          o[nf] = __builtin_amdgcn_mfma_f32_16x16x32_bf16(pa[kf], vb, o[nf], 0, 0, 0);
        }
    }

    // epilogue
#pragma unroll
    for (int r = 0; r < 4; ++r) {
      float lt = l_i[r];
#pragma unroll
      for (int d = 8; d; d >>= 1) lt += __shfl_xor(lt, d);
      float inv = 1.0f / lt;
      int sg = qbase + quad * 4 + r;
#pragma unroll
      for (int nf = 0; nf < 8; ++nf)
        obuf[(size_t)sg * OD + h * HD + nf * 16 + col] = f2bf(o[nf][r] * inv);
    }
  }
}

// ---------------- launcher ----------------
extern "C" void kernel_launch(void* const* d_in, const int* in_sizes, int n_in,
                              void* d_out, int out_size, void* d_ws, size_t ws_size,
                              hipStream_t stream) {
  (void)in_sizes; (void)n_in; (void)out_size; (void)ws_size;
  const float* hs   = (const float*)d_in[0];   // [2048][2048] f32
  const int*   pos  = (const int*)d_in[1];     // [2048] int32
  const float* qkvw = (const float*)d_in[2];   // [12288][2048] f32
  const float* qw   = (const float*)d_in[3];   // [128] f32
  const float* kw   = (const float*)d_in[4];   // [128] f32
  const float* ow   = (const float*)d_in[5];   // [2048][4096] f32
  float* out = (float*)d_out;                  // [2048][2048] f32

  // Memory plan: ws[0..48M) qkvb, ws[48..64M) obuf.
  // d_out: hsb (bf16 hidden) during GEMM1 -> vtp (packed V^T) -> final out (GEMM2).
  char* ws = (char*)d_ws;
  short* qkvb = (short*)(ws);
  short* obuf = (short*)(ws + 50331648);
  short* hsb  = (short*)d_out;
  short* vtp  = (short*)d_out;

  // 1) convert hidden_states -> bf16 (in d_out scratch)
  {
    int n4 = (S_LEN * HID) / 4;
    convert_kernel<<<(n4 + 255) / 256, 256, 0, stream>>>(hs, hsb, n4);
  }

  // 2) qkv = hs @ qkv_w^T, single launch, B f32 direct (M=2048, N=12288, K=2048)
  gemm_nt_f32w<128, 0><<<dim3(QKV_O / 128, S_LEN / BM), 256, 0, stream>>>(
      hsb, qkvw, qkvb, HID, QKV_O);

  // 3) RMSNorm + RoPE in place on q,k (q pre-scaled by scale*log2e)
  norm_rope_kernel<<<(S_LEN * 2 * NH) / 4, 256, 0, stream>>>(qkvb, pos, qw, kw);

  // 4) pack V^T tiles into d_out (hsb dead after GEMM1)
  packv_kernel<<<dim3(NH, S_LEN / 64), 256, 0, stream>>>(qkvb, vtp);

  // 5) causal flash attention -> obuf [s][h*128+d] (bf16)
  attn_kernel<<<dim3(16, NH), 256, 0, stream>>>(qkvb, vtp, obuf);

  // 6) out = obuf @ o_proj_w^T, B f32 direct, 128x64 tile (512 blocks), fp32 C
  gemm_nt_f32w<64, 1><<<dim3(HID / 64, S_LEN / BM), 256, 0, stream>>>(
      obuf, ow, out, OD, HID);
}

// Round 10
// 559.566 us; speedup vs baseline: 1.1332x; 1.0432x over previous
//
#include <hip/hip_runtime.h>
#include <cstdint>
#include <cstddef>

// ---- problem constants ----
static constexpr int S_LEN = 2048;
static constexpr int HID   = 2048;
static constexpr int NH    = 32;
static constexpr int HD    = 128;
static constexpr int OD    = 4096;    // NH*HD
static constexpr int QKV_O = 12288;   // 3*OD

#define AS1 __attribute__((address_space(1)))
#define AS3 __attribute__((address_space(3)))

typedef __attribute__((ext_vector_type(8))) short bf16x8;
typedef __attribute__((ext_vector_type(4))) float f32x4;
typedef __attribute__((ext_vector_type(4))) short s16x4;

__device__ __forceinline__ short f2bf(float f) {
  unsigned u = __float_as_uint(f);
  unsigned r = (u + 0x7fffu + ((u >> 16) & 1u)) >> 16;   // RNE
  return (short)r;
}
__device__ __forceinline__ float bf2f(short s) {
  return __uint_as_float(((unsigned)(unsigned short)s) << 16);
}
// pack two f32 -> two bf16 (truncation) in ONE v_perm: low short = a.hi16, high = b.hi16
__device__ __forceinline__ unsigned pk2bf(float a, float b) {
  return __builtin_amdgcn_perm(__float_as_uint(b), __float_as_uint(a), 0x07060302u);
}

// ---------------- fp32 -> bf16 convert (bandwidth-bound) ----------------
__global__ void convert_kernel(const float* __restrict__ in, short* __restrict__ out, int n4) {
  int i = blockIdx.x * blockDim.x + threadIdx.x;
  if (i >= n4) return;
  float4 f = ((const float4*)in)[i];
  s16x4 s;
  s.x = f2bf(f.x); s.y = f2bf(f.y); s.z = f2bf(f.z); s.w = f2bf(f.w);
  ((s16x4*)out)[i] = s;
}

// ---------------- NT GEMM: C[M,N] = A[M,K](bf16) * B[N,K]^T(f32, direct) ----------------
// B f32 tile XOR-swizzled in LDS (source-address permuted; LDS dest stays wave-linear).
// B fragments converted f32->bf16 via packed v_perm truncation (4 VALU per 8 elems).
// BNT: tile N (128 or 64).  CMODE: 0 = bf16 C, 1 = fp32 C.  ldc = C row stride.
#define BM 128
#define BK 32

template <int BNT, int CMODE>
__global__ __launch_bounds__(256, 2) void gemm_nt_f32w(
    const short* __restrict__ A, const float* __restrict__ B, void* __restrict__ Cp,
    int K, int ldc) {
  __shared__ short Alds[BM * BK];      // 8 KB bf16
  __shared__ float B32[BNT * BK];      // 16/8 KB f32, swizzled
  constexpr int WN = BNT / 2;          // per-wave cols
  constexpr int NJ = WN / 16;          // B frags per wave
  constexpr int BIT = BNT * 8 / 256;   // B staging iterations (16B chunks)
  const int tid  = threadIdx.x;
  const int lane = tid & 63;
  const int quad = lane >> 4;
  const int col  = lane & 15;
  const int wave = tid >> 6;
  const int m0 = blockIdx.y * BM;
  const int n0 = blockIdx.x * BNT;
  const int wm = (wave & 1) * 64;
  const int wn = (wave >> 1) * WN;

  f32x4 acc[4][NJ] = {};

  for (int k0 = 0; k0 < K; k0 += BK) {
    __syncthreads();
    // --- stage A (bf16, linear) ---
#pragma unroll
    for (int it = 0; it < 2; ++it) {
      int idx = it * 256 + tid;
      int row = idx >> 2;
      int ce  = (idx & 3) * 8;
      const short* ga = A + (size_t)(m0 + row) * K + k0 + ce;
      __builtin_amdgcn_global_load_lds((const AS1 unsigned*)ga, (AS3 unsigned*)&Alds[idx * 8], 16, 0, 0);
    }
    // --- stage B (f32, source-permuted so LDS is chunk-swizzled) ---
#pragma unroll
    for (int it = 0; it < BIT; ++it) {
      int idx  = it * 256 + tid;        // LDS 16B-chunk index
      int row  = idx >> 3;
      int gsrc = (idx & 7) ^ (row & 7); // inverse swizzle on the source
      const float* gb = B + (size_t)(n0 + row) * K + k0 + gsrc * 4;
      __builtin_amdgcn_global_load_lds((const AS1 unsigned*)gb, (AS3 unsigned*)&B32[idx * 4], 16, 0, 0);
    }
    __syncthreads();

    bf16x8 a[4], b[NJ];
#pragma unroll
    for (int i = 0; i < 4; ++i)
      a[i] = *(const bf16x8*)&Alds[(wm + i * 16 + col) * BK + quad * 8];
#pragma unroll
    for (int j = 0; j < NJ; ++j) {
      int row = wn + j * 16 + col;
      int r7  = row & 7;
      union { unsigned u[4]; bf16x8 v; } pk;
#pragma unroll
      for (int j4 = 0; j4 < 2; ++j4) {
        int g = quad * 2 + j4;
        const float4 f = *(const float4*)&B32[(row * 8 + (g ^ r7)) * 4];
        pk.u[j4 * 2 + 0] = pk2bf(f.x, f.y);
        pk.u[j4 * 2 + 1] = pk2bf(f.z, f.w);
      }
      b[j] = pk.v;
    }
#pragma unroll
    for (int i = 0; i < 4; ++i)
#pragma unroll
      for (int j = 0; j < NJ; ++j)
        acc[i][j] = __builtin_amdgcn_mfma_f32_16x16x32_bf16(a[i], b[j], acc[i][j], 0, 0, 0);
  }

  // epilogue: C/D layout col=lane&15, row=quad*4+reg (verified m89/m91)
#pragma unroll
  for (int i = 0; i < 4; ++i)
#pragma unroll
    for (int j = 0; j < NJ; ++j)
#pragma unroll
      for (int r = 0; r < 4; ++r) {
        int rr = m0 + wm + i * 16 + quad * 4 + r;
        int cc = n0 + wn + j * 16 + col;
        if (CMODE == 1)
          ((float*)Cp)[(size_t)rr * ldc + cc] = acc[i][j][r];
        else
          ((short*)Cp)[(size_t)rr * ldc + cc] = f2bf(acc[i][j][r]);
      }
}

// ---------------- per-(s, q/k, head) RMSNorm + RoPE, in place on bf16 qkv ----------------
// Q rows are additionally pre-scaled by scale*log2(e) (softmax folding).
__global__ void norm_rope_kernel(short* __restrict__ qkv,
                                 const int* __restrict__ positions,
                                 const float* __restrict__ qw,
                                 const float* __restrict__ kw) {
  int item = blockIdx.x * 4 + (threadIdx.x >> 6);  // (s, which, head)
  int lane = threadIdx.x & 63;
  int head  = item & 31;
  int which = (item >> 5) & 1;
  int s     = item >> 6;
  const float* w = which ? kw : qw;
  short* base = qkv + (size_t)s * QKV_O + which * OD + head * HD;

  float x1 = bf2f(base[lane]);
  float x2 = bf2f(base[lane + 64]);
  float ss = x1 * x1 + x2 * x2;
#pragma unroll
  for (int d = 32; d; d >>= 1) ss += __shfl_xor(ss, d);
  float r = rsqrtf(ss * (1.0f / 128.0f) + 1e-5f);
  float xn1 = x1 * r * w[lane];
  float xn2 = x2 * r * w[lane + 64];

  float pos = (float)positions[s];
  float inv_freq = exp2f((float)lane * (-13.287712379549449f / 64.0f));
  float f = pos * inv_freq;
  float c = cosf(f), sn = sinf(f);
  float sc = which ? 1.0f : 0.12751863738f;   // q: fold scale*log2(e)
  base[lane]      = f2bf((xn1 * c - xn2 * sn) * sc);
  base[lane + 64] = f2bf((xn2 * c + xn1 * sn) * sc);
}

// ---------------- V pre-transpose: qkv V region -> vtp[h][kt][d][64] tiles ----------------
__global__ void packv_kernel(const short* __restrict__ qkv, short* __restrict__ vtp) {
  __shared__ short T[64][136];   // +8 pad
  const int h  = blockIdx.x;
  const int kt = blockIdx.y;
  const int tid = threadIdx.x;
  {
    int rr = tid >> 2;
    int db = (tid & 3) * 32;
    const short* src = qkv + (size_t)(kt * 64 + rr) * QKV_O + 2 * OD + h * HD + db;
#pragma unroll
    for (int i = 0; i < 4; ++i)
      *(bf16x8*)&T[rr][db + i * 8] = *(const bf16x8*)(src + i * 8);
  }
  __syncthreads();
  {
    int d  = tid >> 1;
    int k0 = (tid & 1) * 32;
    short* dst = vtp + (((size_t)h * 32 + kt) * 128 + d) * 64 + k0;
#pragma unroll
    for (int c = 0; c < 4; ++c) {
      bf16x8 v;
#pragma unroll
      for (int j = 0; j < 8; ++j) v[j] = T[k0 + c * 8 + j][d];
      *(bf16x8*)&dst[c * 8] = v;
    }
  }
}

// ---------------- flash attention (causal), Bq=64/Bk=64 paired, swizzled LDS ----------------
__global__ __launch_bounds__(256, 2) void attn_kernel(
    const short* __restrict__ qkv, const short* __restrict__ vtp, short* __restrict__ obuf) {
  __shared__ short Klds[64 * 128];     // 16 KB
  __shared__ short Vt[128 * 64];       // 16 KB
  __shared__ short Plds[4][16 * 64];   //  8 KB

  const int tid  = threadIdx.x;
  const int lane = tid & 63;
  const int wave = tid >> 6;
  const int quad = lane >> 4;
  const int col  = lane & 15;
  const int h    = blockIdx.y;

#pragma unroll 1
  for (int half = 0; half < 2; ++half) {
    const int qt = half == 0 ? blockIdx.x : 31 - blockIdx.x;   // paired: 33 k-iters/block
    const int qbase = qt * 64 + wave * 16;

    bf16x8 qf[4];
#pragma unroll
    for (int kf = 0; kf < 4; ++kf)
      qf[kf] = *(const bf16x8*)(qkv + (size_t)(qbase + col) * QKV_O + h * HD + kf * 32 + quad * 8);

    f32x4 o[8] = {};
    float m_r[4], l_i[4];
#pragma unroll
    for (int r = 0; r < 4; ++r) { m_r[r] = -1e30f; l_i[r] = 0.f; }

    for (int kt = 0; kt <= qt; ++kt) {
      __syncthreads();
      {
        int r  = tid >> 2;            // key 0..63
        int cb = (tid & 3) * 32;
        const short* kp = qkv + (size_t)(kt * 64 + r) * QKV_O + OD + h * HD + cb;
#pragma unroll
        for (int i = 0; i < 4; ++i) {
          int swz = ((tid & 3) * 4 + i) ^ (r & 15);
          *(bf16x8*)&Klds[r * 128 + swz * 8] = *(const bf16x8*)(kp + i * 8);
        }
        int vd = tid >> 1;            // d 0..127
        const short* vp = vtp + (((size_t)h * 32 + kt) * 128 + vd) * 64 + (tid & 1) * 32;
#pragma unroll
        for (int i = 0; i < 4; ++i) {
          int swz = ((tid & 1) * 4 + i) ^ (vd & 7);
          *(bf16x8*)&Vt[vd * 64 + swz * 8] = *(const bf16x8*)(vp + i * 8);
        }
      }
      __syncthreads();

      // S = Q K^T
      f32x4 sfr[4];
#pragma unroll
      for (int nf = 0; nf < 4; ++nf) {
        f32x4 acc = {};
#pragma unroll
        for (int kf = 0; kf < 4; ++kf) {
          bf16x8 b = *(const bf16x8*)&Klds[(nf * 16 + col) * 128 + ((kf * 4 + quad) ^ col) * 8];
          acc = __builtin_amdgcn_mfma_f32_16x16x32_bf16(qf[kf], b, acc, 0, 0, 0);
        }
        sfr[nf] = acc;
      }

      if (kt == qt) {   // diagonal tile: causal mask
#pragma unroll
        for (int nf = 0; nf < 4; ++nf)
#pragma unroll
          for (int r = 0; r < 4; ++r) {
            int key = kt * 64 + nf * 16 + col;
            int qg  = qbase + quad * 4 + r;
            if (key > qg) sfr[nf][r] = -1e30f;
          }
      }

      // online softmax (log2 domain, per-lane partial l)
#pragma unroll
      for (int r = 0; r < 4; ++r) {
        float mt = fmaxf(fmaxf(sfr[0][r], sfr[1][r]), fmaxf(sfr[2][r], sfr[3][r]));
#pragma unroll
        for (int d = 8; d; d >>= 1) mt = fmaxf(mt, __shfl_xor(mt, d));
        float mnew  = fmaxf(m_r[r], mt);
        float alpha = exp2f(m_r[r] - mnew);
        float ps = 0.f;
#pragma unroll
        for (int nf = 0; nf < 4; ++nf) {
          float p = exp2f(sfr[nf][r] - mnew);
          sfr[nf][r] = p;
          ps += p;
        }
        l_i[r] = l_i[r] * alpha + ps;
        m_r[r] = mnew;
#pragma unroll
        for (int nf = 0; nf < 8; ++nf) o[nf][r] *= alpha;
      }

      // P -> per-wave LDS (C-layout scatter -> A-layout rows), swizzled
#pragma unroll
      for (int nf = 0; nf < 4; ++nf)
#pragma unroll
        for (int r = 0; r < 4; ++r) {
          int row = quad * 4 + r;
          int key = nf * 16 + col;
          Plds[wave][row * 64 + ((key >> 3) ^ (row & 7)) * 8 + (key & 7)] = f2bf(sfr[nf][r]);
        }

      // O += P V
      bf16x8 pa[2];
#pragma unroll
      for (int kf = 0; kf < 2; ++kf)
        pa[kf] = *(const bf16x8*)&Plds[wave][col * 64 + ((kf * 4 + quad) ^ (col & 7)) * 8];
#pragma unroll
      for (int nf = 0; nf < 8; ++nf)
#pragma unroll
        for (int kf = 0; kf < 2; ++kf) {
          bf16x8 vb = *(const bf16x8*)&Vt[(nf * 16 + col) * 64 + ((kf * 4 + quad) ^ (col & 7)) * 8];
          o[nf] = __builtin_amdgcn_mfma_f32_16x16x32_bf16(pa[kf], vb, o[nf], 0, 0, 0);
        }
    }

    // epilogue
#pragma unroll
    for (int r = 0; r < 4; ++r) {
      float lt = l_i[r];
#pragma unroll
      for (int d = 8; d; d >>= 1) lt += __shfl_xor(lt, d);
      float inv = 1.0f / lt;
      int sg = qbase + quad * 4 + r;
#pragma unroll
      for (int nf = 0; nf < 8; ++nf)
        obuf[(size_t)sg * OD + h * HD + nf * 16 + col] = f2bf(o[nf][r] * inv);
    }
  }
}

// ---------------- launcher ----------------
extern "C" void kernel_launch(void* const* d_in, const int* in_sizes, int n_in,
                              void* d_out, int out_size, void* d_ws, size_t ws_size,
                              hipStream_t stream) {
  (void)in_sizes; (void)n_in; (void)out_size; (void)ws_size;
  const float* hs   = (const float*)d_in[0];   // [2048][2048] f32
  const int*   pos  = (const int*)d_in[1];     // [2048] int32
  const float* qkvw = (const float*)d_in[2];   // [12288][2048] f32
  const float* qw   = (const float*)d_in[3];   // [128] f32
  const float* kw   = (const float*)d_in[4];   // [128] f32
  const float* ow   = (const float*)d_in[5];   // [2048][4096] f32
  float* out = (float*)d_out;                  // [2048][2048] f32

  // Memory plan: ws[0..48M) qkvb, ws[48..64M) obuf.
  // d_out: hsb (bf16 hidden) during GEMM1 -> vtp (packed V^T) -> final out (GEMM2).
  char* ws = (char*)d_ws;
  short* qkvb = (short*)(ws);
  short* obuf = (short*)(ws + 50331648);
  short* hsb  = (short*)d_out;
  short* vtp  = (short*)d_out;

  // 1) convert hidden_states -> bf16 (in d_out scratch)
  {
    int n4 = (S_LEN * HID) / 4;
    convert_kernel<<<(n4 + 255) / 256, 256, 0, stream>>>(hs, hsb, n4);
  }

  // 2) qkv = hs @ qkv_w^T, single launch, B f32 direct (M=2048, N=12288, K=2048)
  gemm_nt_f32w<128, 0><<<dim3(QKV_O / 128, S_LEN / BM), 256, 0, stream>>>(
      hsb, qkvw, qkvb, HID, QKV_O);

  // 3) RMSNorm + RoPE in place on q,k (q pre-scaled by scale*log2e)
  norm_rope_kernel<<<(S_LEN * 2 * NH) / 4, 256, 0, stream>>>(qkvb, pos, qw, kw);

  // 4) pack V^T tiles into d_out (hsb dead after GEMM1)
  packv_kernel<<<dim3(NH, S_LEN / 64), 256, 0, stream>>>(qkvb, vtp);

  // 5) causal flash attention -> obuf [s][h*128+d] (bf16)
  attn_kernel<<<dim3(16, NH), 256, 0, stream>>>(qkvb, vtp, obuf);

  // 6) out = obuf @ o_proj_w^T, B f32 direct, 128x64 tile (512 blocks), fp32 C
  gemm_nt_f32w<64, 1><<<dim3(HID / 64, S_LEN / BM), 256, 0, stream>>>(
      obuf, ow, out, OD, HID);
}